// Round 1
// baseline (19303.577 us; speedup 1.0000x reference)
//
#include <hip/hip_runtime.h>
#include <math.h>

#define T_STEPS 16384
#define IN_DIM  14
#define H_DIM   100
#define G_DIM   300   // 3*H

// ---------------- Phase 0: gi0[t][j] = b_ih0[j] + sum_k x[t][k]*w_ih0[j][k] ----------------
__global__ void gi0_kernel(const float* __restrict__ x,
                           const float* __restrict__ w_ih0,
                           const float* __restrict__ b_ih0,
                           float* __restrict__ gi0) {
    int e = blockIdx.x * blockDim.x + threadIdx.x;
    if (e >= T_STEPS * G_DIM) return;
    int t = e / G_DIM;
    int j = e - t * G_DIM;
    const float* xr = x + t * IN_DIM;
    const float* wr = w_ih0 + j * IN_DIM;
    float acc = b_ih0[j];
    #pragma unroll
    for (int k = 0; k < IN_DIM; ++k) acc = fmaf(xr[k], wr[k], acc);
    gi0[e] = acc;
}

// ---------------- Phase 1: persistent single-workgroup sequential GRU ----------------
__device__ __forceinline__ float sig_(float x) { return 1.0f / (1.0f + expf(-x)); }

__global__ __launch_bounds__(960, 4)
void gru_seq_kernel(const float* __restrict__ gi0,
                    const float* __restrict__ w_hh0,
                    const float* __restrict__ b_hh0,
                    const float* __restrict__ w_ih1,
                    const float* __restrict__ b_ih1,
                    const float* __restrict__ w_hh1,
                    const float* __restrict__ b_hh1,
                    const float* __restrict__ fc_w,
                    const float* __restrict__ fc_b,
                    float* __restrict__ out) {
    // h1 at hbuf[0..100), h2 at hbuf[128..228) — single array so addrspace stays LDS
    __shared__ __align__(16) float hbuf[256];
    __shared__ float gh[3 * G_DIM];   // [0,300)=ghA(l0 rec), [300,600)=gi1 (l1 in-proj), [600,900)=ghC(l1 rec)

    const int tid = threadIdx.x;
    const int group = tid / 320;            // 0: l0-recurrent, 1: l1-input, 2: l1-recurrent
    const int lig = tid - group * 320;
    const bool active = lig < G_DIM;
    const int row = active ? lig : 0;

    const float* wsrc;
    float bias;
    if (group == 0)      { wsrc = w_hh0 + row * H_DIM; bias = b_hh0[row]; }
    else if (group == 1) { wsrc = w_ih1 + row * H_DIM; bias = b_ih1[row]; }
    else                 { wsrc = w_hh1 + row * H_DIM; bias = b_hh1[row]; }
    const int hoff4 = (group == 2) ? 32 : 0;   // float4 index of h2 vs h1
    const int ghidx = group * G_DIM + row;

    // Load this thread's weight row into registers (100 VGPRs)
    float w[H_DIM];
    {
        const float4* wp = reinterpret_cast<const float4*>(wsrc);
        #pragma unroll
        for (int k = 0; k < H_DIM / 4; ++k) {
            float4 v = wp[k];
            w[4*k+0] = v.x; w[4*k+1] = v.y; w[4*k+2] = v.z; w[4*k+3] = v.w;
        }
    }

    // init h1 = h2 = 0
    if (tid < H_DIM) hbuf[tid] = 0.0f;
    else if (tid >= 128 && tid < 128 + H_DIM) hbuf[tid] = 0.0f;
    __syncthreads();

    const float4* hb4 = reinterpret_cast<const float4*>(hbuf);

    for (int i = 0; i <= T_STEPS; ++i) {
        // Prefetch gi0 row i (gate threads); covered by the dot phase before use
        float gr = 0.f, gz = 0.f, gn = 0.f;
        if (tid < H_DIM && i < T_STEPS) {
            const float* p = gi0 + i * G_DIM + tid;
            gr = p[0]; gz = p[H_DIM]; gn = p[2 * H_DIM];
        }

        // Dot phase: all three stages in parallel against h1[i-1] / h2[i-2]
        float acc = bias;
        #pragma unroll
        for (int k = 0; k < H_DIM / 4; ++k) {
            float4 v = hb4[hoff4 + k];
            acc = fmaf(w[4*k+0], v.x, acc);
            acc = fmaf(w[4*k+1], v.y, acc);
            acc = fmaf(w[4*k+2], v.z, acc);
            acc = fmaf(w[4*k+3], v.w, acc);
        }
        if (active) gh[ghidx] = acc;
        __syncthreads();

        // Gate phase
        if (tid < H_DIM) {
            if (i < T_STEPS) {   // produce h1[i]
                float r = sig_(gr + gh[tid]);
                float z = sig_(gz + gh[H_DIM + tid]);
                float n = tanhf(gn + r * gh[2 * H_DIM + tid]);
                float hp = hbuf[tid];
                hbuf[tid] = (1.0f - z) * n + z * hp;
            }
        } else if (tid >= 640 && tid < 640 + H_DIM) {
            if (i >= 1) {        // produce h2[i-1]
                int j = tid - 640;
                float r = sig_(gh[G_DIM + j] + gh[2 * G_DIM + j]);
                float z = sig_(gh[G_DIM + H_DIM + j] + gh[2 * G_DIM + H_DIM + j]);
                float n = tanhf(gh[G_DIM + 2 * H_DIM + j] + r * gh[2 * G_DIM + 2 * H_DIM + j]);
                float hp = hbuf[128 + j];
                hbuf[128 + j] = (1.0f - z) * n + z * hp;
            }
        }
        __syncthreads();
    }

    // FC epilogue: out = fc_b + fc_w . h2[T-1]
    if (tid < 64) {
        float s = 0.0f;
        for (int j = tid; j < H_DIM; j += 64) s = fmaf(fc_w[j], hbuf[128 + j], s);
        #pragma unroll
        for (int off = 32; off > 0; off >>= 1) s += __shfl_down(s, off);
        if (tid == 0) out[0] = s + fc_b[0];
    }
}

extern "C" void kernel_launch(void* const* d_in, const int* in_sizes, int n_in,
                              void* d_out, int out_size, void* d_ws, size_t ws_size,
                              hipStream_t stream) {
    const float* x     = (const float*)d_in[0];
    const float* w_ih0 = (const float*)d_in[1];
    const float* w_hh0 = (const float*)d_in[2];
    const float* b_ih0 = (const float*)d_in[3];
    const float* b_hh0 = (const float*)d_in[4];
    const float* w_ih1 = (const float*)d_in[5];
    const float* w_hh1 = (const float*)d_in[6];
    const float* b_ih1 = (const float*)d_in[7];
    const float* b_hh1 = (const float*)d_in[8];
    const float* fc_w  = (const float*)d_in[9];
    const float* fc_b  = (const float*)d_in[10];
    float* out = (float*)d_out;
    float* gi0 = (float*)d_ws;   // T*300 floats = 19.66 MB

    const int total = T_STEPS * G_DIM;
    gi0_kernel<<<(total + 255) / 256, 256, 0, stream>>>(x, w_ih0, b_ih0, gi0);
    gru_seq_kernel<<<1, 960, 0, stream>>>(gi0, w_hh0, b_hh0, w_ih1, b_ih1,
                                          w_hh1, b_hh1, fc_w, fc_b, out);
}